// Round 11
// baseline (800.765 us; speedup 1.0000x reference)
//
#include <hip/hip_runtime.h>

#define NN 50000
#define NE 800000
#define NG 128
#define RREP 16
#define RSTRIDE 50048

typedef __attribute__((ext_vector_type(8))) short short8;
typedef __attribute__((ext_vector_type(4))) float f32x4;

// round-half-up bf16 convert: 2 VALU ops, max err 0.5 ulp
__device__ __forceinline__ unsigned short f2bf(float f){
  union { float f; unsigned int u; } v; v.f = f;
  return (unsigned short)((v.u + 0x8000u) >> 16);
}
__device__ __forceinline__ float bf2f(unsigned short h){
  union { unsigned int u; float f; } v; v.u = ((unsigned int)h) << 16;
  return v.f;
}

// ---------------- graph offsets from SORTED graph_ids: boundary scan, zero atomics ----------------
__global__ __launch_bounds__(256) void k_goff(const int* __restrict__ gid,
                                              int* __restrict__ goff){
  int i = blockIdx.x*256 + threadIdx.x;
  if (i >= NN) return;
  int c = gid[i];
  int p = (i == 0) ? -1 : gid[i-1];
  for (int g = p+1; g <= c; ++g) goff[g] = i;
  if (i == NN-1){
    for (int g = c+1; g <= NG; ++g) goff[g] = NN;
  }
}

// ---------------- CSR build (16-way replicated histograms) ----------------
__global__ __launch_bounds__(256) void k_count_rep(const int* __restrict__ idx,
                                                   int* __restrict__ cnt_rep, int n){
  int i = blockIdx.x*256 + threadIdx.x;
  int r = blockIdx.x & (RREP-1);
  if (i < n) atomicAdd(&cnt_rep[r*RSTRIDE + idx[i]], 1);
}

__global__ __launch_bounds__(256) void k_reduce_rep(const int* __restrict__ cnt_rep,
                                                    int* __restrict__ cnt){
  int i = blockIdx.x*256 + threadIdx.x;
  if (i < NN){
    int s = 0;
    #pragma unroll
    for (int r=0; r<RREP; ++r) s += cnt_rep[r*RSTRIDE + i];
    cnt[i] = s;
  }
}

__global__ __launch_bounds__(256) void k_blocksum(const int* __restrict__ in, int n,
                                                  int* __restrict__ bsum){
  __shared__ int ws4[4];
  int i = blockIdx.x*256 + threadIdx.x;
  int v = (i < n) ? in[i] : 0;
  #pragma unroll
  for (int d=1; d<64; d<<=1) v += __shfl_xor(v, d);
  int lane = threadIdx.x & 63, w = threadIdx.x >> 6;
  if (lane == 0) ws4[w] = v;
  __syncthreads();
  if (threadIdx.x == 0) bsum[blockIdx.x] = ws4[0]+ws4[1]+ws4[2]+ws4[3];
}

// exclusive scan of n<=256 elements, single block of 256; out[n]=total
__global__ __launch_bounds__(256) void k_scan_small(const int* __restrict__ in, int n,
                                                    int* __restrict__ out){
  __shared__ int wsum[4];
  int tid = threadIdx.x, lane = tid & 63, w = tid >> 6;
  int v = (tid < n) ? in[tid] : 0;
  int x = v;
  #pragma unroll
  for (int d=1; d<64; d<<=1){ int y = __shfl_up(x, d); if (lane >= d) x += y; }
  if (lane == 63) wsum[w] = x;
  __syncthreads();
  int pre2 = 0;
  for (int j=0; j<w; ++j) pre2 += wsum[j];
  int incl = x + pre2;
  if (tid < n) out[tid] = incl - v;
  if (tid == n-1) out[n] = incl;
}

__global__ __launch_bounds__(256) void k_scan_apply(const int* __restrict__ in, int n,
                                                    const int* __restrict__ boff,
                                                    int* __restrict__ out){
  __shared__ int wsum[4];
  int tid = threadIdx.x, lane = tid & 63, w = tid >> 6;
  int i = blockIdx.x*256 + tid;
  int v = (i < n) ? in[i] : 0;
  int x = v;
  #pragma unroll
  for (int d=1; d<64; d<<=1){ int y = __shfl_up(x, d); if (lane >= d) x += y; }
  if (lane == 63) wsum[w] = x;
  __syncthreads();
  int pre2 = boff[blockIdx.x];
  for (int j=0; j<w; ++j) pre2 += wsum[j];
  int excl = x - v + pre2;
  if (i < n){
    out[i] = excl;
    if (i == n-1) out[n] = excl + v;
  }
}

// per-replica fill cursors
__global__ __launch_bounds__(256) void k_fpos_rep(const int* __restrict__ cnt_rep,
                                                  const int* __restrict__ off,
                                                  int* __restrict__ fpos_rep){
  int i = blockIdx.x*256 + threadIdx.x;
  if (i < NN){
    int p = off[i];
    #pragma unroll
    for (int r=0; r<RREP; ++r){
      fpos_rep[r*RSTRIDE + i] = p;
      p += cnt_rep[r*RSTRIDE + i];
    }
  }
}

__global__ __launch_bounds__(256) void k_fill_rep(const int* __restrict__ src,
                                                  const int* __restrict__ dst,
                                                  int* __restrict__ fpos_rep,
                                                  int* __restrict__ csr, int n){
  int i = blockIdx.x*256 + threadIdx.x;
  int r = blockIdx.x & (RREP-1);
  if (i < n){
    int p = atomicAdd(&fpos_rep[r*RSTRIDE + dst[i]], 1);
    csr[p] = src[i];
  }
}

// ---------------- weight pre-transpose to bf16 ----------------
__global__ __launch_bounds__(256) void k_wt(const float* __restrict__ Wq,
                                            const float* __restrict__ Wk,
                                            const float* __restrict__ Wv,
                                            const float* __restrict__ Wo,
                                            unsigned short* __restrict__ Wt){
  int gid = blockIdx.x*256 + threadIdx.x;   // 49152 total
  int l   = gid >> 14;
  int rem = gid & 16383;
  int mat = rem >> 12;
  int idx = rem & 4095;
  int c = idx >> 6, n = idx & 63;
  const float* srcp = (mat==0)?Wq:(mat==1)?Wk:(mat==2)?Wv:Wo;
  float v = srcp[l*4096 + idx];
  Wt[l*16384 + (mat*64 + n)*64 + c] = f2bf(v);
}

// ---------------- fp32 -> bf16, CHUNKED pre layout: [8 chunks][NN nodes][32 feats] ----------------
__global__ __launch_bounds__(256) void k_f2bf_c(const float* __restrict__ in,
                                                unsigned short* __restrict__ out){
  int i = blockIdx.x*256 + threadIdx.x;   // ushort4 id, 3,200,000 total
  float4 v = ((const float4*)in)[i];
  ushort4 o; o.x=f2bf(v.x); o.y=f2bf(v.y); o.z=f2bf(v.z); o.w=f2bf(v.w);
  int flat = i << 2;
  int node = flat >> 8, f = flat & 255;
  int chunk = f >> 5;
  ((ushort4*)out)[(size_t)chunk*NN*8 + node*8 + ((f & 31) >> 2)] = o;
}

// ---------------- XCD-pinned chunked CSR gather; nt stores/loads keep L2 for the table ----------------
__global__ __launch_bounds__(256) void k_agg_x(const unsigned short* __restrict__ pre_c,
                                               const int* __restrict__ off,
                                               const int* __restrict__ csr,
                                               unsigned short* __restrict__ agg){
  int chunk = blockIdx.x & 7;
  int seg   = blockIdx.x >> 3;
  int w = threadIdx.x >> 6, lane = threadIdx.x & 63;
  int lg = lane >> 3, li = lane & 7;
  int node = seg*32 + w*8 + lg;
  if (node >= NN) return;
  const ushort4* slice = (const ushort4*)pre_c + (size_t)chunk*NN*8;
  int s = off[node], e = off[node+1];
  ushort4 u = slice[node*8 + li];
  float a0 = bf2f(u.x), a1 = bf2f(u.y), a2 = bf2f(u.z), a3 = bf2f(u.w);
  int i = s;
  for (; i + 2 <= e; i += 2){
    int n0 = __builtin_nontemporal_load(&csr[i]);
    int n1 = __builtin_nontemporal_load(&csr[i+1]);
    ushort4 u0 = slice[n0*8 + li], u1 = slice[n1*8 + li];
    a0 += bf2f(u0.x)+bf2f(u1.x);
    a1 += bf2f(u0.y)+bf2f(u1.y);
    a2 += bf2f(u0.z)+bf2f(u1.z);
    a3 += bf2f(u0.w)+bf2f(u1.w);
  }
  if (i < e){
    int n0 = __builtin_nontemporal_load(&csr[i]);
    ushort4 u0 = slice[n0*8 + li];
    a0 += bf2f(u0.x); a1 += bf2f(u0.y); a2 += bf2f(u0.z); a3 += bf2f(u0.w);
  }
  ushort4 o; o.x=f2bf(a0); o.y=f2bf(a1); o.z=f2bf(a2); o.w=f2bf(a3);
  // nt store: ushort4 (HIP class) not accepted by the builtin -> punch through u64
  union { ushort4 v; unsigned long long u; } cvt; cvt.v = o;
  __builtin_nontemporal_store(cvt.u,
      (unsigned long long*)&((ushort4*)agg)[node*64 + chunk*8 + li]);
}

// ---------------- SAB (r7 proven structure + register agg residual):
// LN -> QKV MFMA -> distributed LDS attention -> O-proj MFMA -> residual -> epilogue
__global__ __launch_bounds__(256) void k_sab(const unsigned short* __restrict__ agg,
                                             unsigned short* __restrict__ h,
                                             unsigned short* __restrict__ lnout,
                                             unsigned short* __restrict__ pre_next,
                                             const unsigned short* __restrict__ Wt,
                                             const float* __restrict__ lng,
                                             const float* __restrict__ lnb,
                                             const float* __restrict__ g2,
                                             const float* __restrict__ b2,
                                             const float* __restrict__ g1,
                                             const float* __restrict__ b1,
                                             int residual, int write_pre, int write_h){
  __shared__ unsigned short xo_s[4][16][72];    // xin -> o -> val (aliased through phases)
  __shared__ unsigned short qkv_s[4][16][200];  // cols 0..63 q, 64..127 k, 128..191 v

  int tid = threadIdx.x;
  int w = tid >> 6, lane = tid & 63;
  int c16 = lane & 15, kb = lane >> 4;
  int R0 = blockIdx.x*64 + w*16;   // 16 contiguous global rows (4 nodes)

  // phase 1: read agg (bf16), keep raw in regs for residual, LN -> bf16 A-staging
  ushort4 av[4];
  {
    float4 gv = ((const float4*)lng)[c16];
    float4 bv = ((const float4*)lnb)[c16];
    #pragma unroll
    for (int rr=0; rr<4; ++rr){
      int m = rr*4 + kb;
      ushort4 uv = ((const ushort4*)agg)[(R0+m)*16 + c16];
      av[rr] = uv;
      float vx = bf2f(uv.x), vy = bf2f(uv.y), vz = bf2f(uv.z), vw = bf2f(uv.w);
      float s = vx+vy+vz+vw;
      float q = vx*vx+vy*vy+vz*vz+vw*vw;
      #pragma unroll
      for (int d=1; d<16; d<<=1){ s += __shfl_xor(s, d); q += __shfl_xor(q, d); }
      float mu = s*(1.f/64.f);
      float rs = rsqrtf(q*(1.f/64.f) - mu*mu + 1e-5f);
      ushort4 o;
      o.x=f2bf((vx-mu)*rs*gv.x+bv.x); o.y=f2bf((vy-mu)*rs*gv.y+bv.y);
      o.z=f2bf((vz-mu)*rs*gv.z+bv.z); o.w=f2bf((vw-mu)*rs*gv.w+bv.w);
      *(ushort4*)&xo_s[w][m][c16*4] = o;
    }
  }

  // phase 2: QKV = xin @ Wqkv  (A-frag: row=c16, k=kb*8+j)
  short8 a0v = *(const short8*)&xo_s[w][c16][kb*8];
  short8 a1v = *(const short8*)&xo_s[w][c16][32 + kb*8];
  f32x4 acc[12];
  #pragma unroll
  for (int t=0; t<12; ++t){
    short8 b0 = *(const short8*)&Wt[(t*16 + c16)*64 + kb*8];
    short8 b1 = *(const short8*)&Wt[(t*16 + c16)*64 + 32 + kb*8];
    f32x4 z = {0.f, 0.f, 0.f, 0.f};
    z = __builtin_amdgcn_mfma_f32_16x16x32_bf16(a0v, b0, z, 0, 0, 0);
    z = __builtin_amdgcn_mfma_f32_16x16x32_bf16(a1v, b1, z, 0, 0, 0);
    acc[t] = z;
  }
  // C/D layout: col=lane&15, row=(lane>>4)*4+reg
  #pragma unroll
  for (int t=0; t<12; ++t){
    #pragma unroll
    for (int r=0; r<4; ++r)
      qkv_s[w][kb*4 + r][t*16 + c16] = f2bf(acc[t][r]);
  }

  // phase 3: distributed attention, per (node, head, q-row) lane (r7, proven)
  {
    int p = lane >> 2, qr = lane & 3;
    int ns = p >> 2, hd = p & 3;
    int mrow = ns*4 + qr;
    int qc = hd*16, kc = 64 + hd*16, vc = 128 + hd*16;
    float qv[16];
    short8 u0 = *(const short8*)&qkv_s[w][mrow][qc];
    short8 u1 = *(const short8*)&qkv_s[w][mrow][qc+8];
    #pragma unroll
    for (int j=0; j<8; ++j){
      qv[j]   = bf2f((unsigned short)u0[j]);
      qv[8+j] = bf2f((unsigned short)u1[j]);
    }
    float sc[4];
    #pragma unroll
    for (int kr=0; kr<4; ++kr){
      short8 k0 = *(const short8*)&qkv_s[w][ns*4+kr][kc];
      short8 k1 = *(const short8*)&qkv_s[w][ns*4+kr][kc+8];
      float d2 = 0.f;
      #pragma unroll
      for (int j=0; j<8; ++j){
        d2 += qv[j]  *bf2f((unsigned short)k0[j]);
        d2 += qv[8+j]*bf2f((unsigned short)k1[j]);
      }
      sc[kr] = d2 * 0.25f;   // 1/sqrt(16)
    }
    float mx = fmaxf(fmaxf(sc[0],sc[1]), fmaxf(sc[2],sc[3]));
    float e0=__expf(sc[0]-mx), e1=__expf(sc[1]-mx), e2=__expf(sc[2]-mx), e3=__expf(sc[3]-mx);
    float inv = 1.f/(e0+e1+e2+e3);
    float at[4] = {e0*inv, e1*inv, e2*inv, e3*inv};
    float ov[16];
    #pragma unroll
    for (int j=0; j<16; ++j) ov[j] = 0.f;
    #pragma unroll
    for (int kr=0; kr<4; ++kr){
      short8 v0 = *(const short8*)&qkv_s[w][ns*4+kr][vc];
      short8 v1 = *(const short8*)&qkv_s[w][ns*4+kr][vc+8];
      #pragma unroll
      for (int j=0; j<8; ++j){
        ov[j]   += at[kr]*bf2f((unsigned short)v0[j]);
        ov[8+j] += at[kr]*bf2f((unsigned short)v1[j]);
      }
    }
    short8 s0v, s1v;
    #pragma unroll
    for (int j=0; j<8; ++j){
      s0v[j] = (short)f2bf(ov[j]);
      s1v[j] = (short)f2bf(ov[8+j]);
    }
    *(short8*)&xo_s[w][mrow][qc]   = s0v;
    *(short8*)&xo_s[w][mrow][qc+8] = s1v;
  }

  // phase 4: val = o @ Wo, C-layout -> LDS (back to row-major view)
  {
    short8 oa0 = *(const short8*)&xo_s[w][c16][kb*8];
    short8 oa1 = *(const short8*)&xo_s[w][c16][32 + kb*8];
    #pragma unroll
    for (int t=0; t<4; ++t){
      short8 b0 = *(const short8*)&Wt[(192 + t*16 + c16)*64 + kb*8];
      short8 b1 = *(const short8*)&Wt[(192 + t*16 + c16)*64 + 32 + kb*8];
      f32x4 z = {0.f, 0.f, 0.f, 0.f};
      z = __builtin_amdgcn_mfma_f32_16x16x32_bf16(oa0, b0, z, 0, 0, 0);
      z = __builtin_amdgcn_mfma_f32_16x16x32_bf16(oa1, b1, z, 0, 0, 0);
      #pragma unroll
      for (int r=0; r<4; ++r)
        xo_s[w][kb*4 + r][t*16 + c16] = f2bf(z[r]);
    }
  }

  // epilogue: coalesced ushort4 streams; iter rr handles row m=rr*4+kb (matches av[rr])
  float4 g2v = ((const float4*)g2)[c16];
  float4 b2v = ((const float4*)b2)[c16];
  float4 g1v, b1v;
  if (write_pre){ g1v = ((const float4*)g1)[c16]; b1v = ((const float4*)b1)[c16]; }
  #pragma unroll
  for (int rr=0; rr<4; ++rr){
    int m = rr*4 + kb;
    int row = R0 + m;
    ushort4 uv = *(const ushort4*)&xo_s[w][m][c16*4];
    float v0 = bf2f(uv.x), v1 = bf2f(uv.y), v2 = bf2f(uv.z), v3 = bf2f(uv.w);
    if (residual){
      ushort4 hh = ((const ushort4*)h)[row*16 + c16];
      v0 += bf2f(hh.x) + bf2f(av[rr].x);
      v1 += bf2f(hh.y) + bf2f(av[rr].y);
      v2 += bf2f(hh.z) + bf2f(av[rr].z);
      v3 += bf2f(hh.w) + bf2f(av[rr].w);
    }
    float r0 = fmaxf(v0,0.f), r1 = fmaxf(v1,0.f), r2 = fmaxf(v2,0.f), r3 = fmaxf(v3,0.f);
    float s1 = v0+v1+v2+v3, q1 = v0*v0+v1*v1+v2*v2+v3*v3;
    float s2 = r0+r1+r2+r3, q2 = r0*r0+r1*r1+r2*r2+r3*r3;
    #pragma unroll
    for (int d=1; d<16; d<<=1){
      s1 += __shfl_xor(s1, d); q1 += __shfl_xor(q1, d);
      s2 += __shfl_xor(s2, d); q2 += __shfl_xor(q2, d);
    }
    float mu1 = s1*(1.f/64.f), rs1 = rsqrtf(q1*(1.f/64.f) - mu1*mu1 + 1e-5f);
    float mu2 = s2*(1.f/64.f), rs2 = rsqrtf(q2*(1.f/64.f) - mu2*mu2 + 1e-5f);
    if (write_h){
      ushort4 o; o.x=f2bf(v0); o.y=f2bf(v1); o.z=f2bf(v2); o.w=f2bf(v3);
      ((ushort4*)h)[row*16 + c16] = o;
    }
    {
      ushort4 o;
      o.x=f2bf((r0-mu2)*rs2*g2v.x+b2v.x); o.y=f2bf((r1-mu2)*rs2*g2v.y+b2v.y);
      o.z=f2bf((r2-mu2)*rs2*g2v.z+b2v.z); o.w=f2bf((r3-mu2)*rs2*g2v.w+b2v.w);
      ((ushort4*)lnout)[row*16 + c16] = o;
    }
    if (write_pre){
      int nd = row >> 2;
      int f = (row & 3)*64 + 4*c16;
      int chunk = f >> 5;
      ushort4 o;
      o.x=f2bf((v0-mu1)*rs1*g1v.x+b1v.x); o.y=f2bf((v1-mu1)*rs1*g1v.y+b1v.y);
      o.z=f2bf((v2-mu1)*rs1*g1v.z+b1v.z); o.w=f2bf((v3-mu1)*rs1*g1v.w+b1v.w);
      ((ushort4*)pre_next)[(size_t)chunk*NN*8 + nd*8 + ((f & 31) >> 2)] = o;
    }
  }
}

// ---------------- per-graph pooling: 8 sub-blocks per graph, atomic merge ----------------
__global__ __launch_bounds__(256) void k_pool8(const float* __restrict__ src,
                                               const int* __restrict__ goff,
                                               float* __restrict__ out){
  int g = blockIdx.x >> 3, sub = blockIdx.x & 7, t = threadIdx.x;
  int s = goff[g], e = goff[g+1], len = e - s;
  int s0 = s + ((len*sub) >> 3), e0 = s + ((len*(sub+1)) >> 3);
  float a0=0.f, a1=0.f;
  int n = s0;
  for (; n + 2 <= e0; n += 2){ a0 += src[n*256 + t]; a1 += src[(n+1)*256 + t]; }
  if (n < e0) a0 += src[n*256 + t];
  atomicAdd(&out[g*256 + t], a0 + a1);
}

__global__ __launch_bounds__(256) void k_pool8b(const unsigned short* __restrict__ src,
                                                const int* __restrict__ goff,
                                                float* __restrict__ out){
  int g = blockIdx.x >> 3, sub = blockIdx.x & 7, t = threadIdx.x;
  int s = goff[g], e = goff[g+1], len = e - s;
  int s0 = s + ((len*sub) >> 3), e0 = s + ((len*(sub+1)) >> 3);
  float a0=0.f, a1=0.f;
  int n = s0;
  for (; n + 2 <= e0; n += 2){ a0 += bf2f(src[n*256 + t]); a1 += bf2f(src[(n+1)*256 + t]); }
  if (n < e0) a0 += bf2f(src[n*256 + t]);
  atomicAdd(&out[g*256 + t], a0 + a1);
}

// ---------------- final: score = sum_i pooled_i @ W_pred[i] + b_pred[i] ----------------
__global__ __launch_bounds__(256) void k_final(const float* __restrict__ pooled,
                                               const float* __restrict__ Wp,
                                               const float* __restrict__ bp,
                                               float* __restrict__ out){
  int t = blockIdx.x*256 + threadIdx.x;  // 8192 = 128*4*16
  int b = t >> 6, s = (t >> 4) & 3, o = t & 15;
  float acc = 0.f;
  for (int i=0; i<4; ++i){
    acc += bp[i*16 + o];
    const float* pr = pooled + i*32768 + b*256 + s*64;
    const float* wp = Wp + i*1024 + o;
    float a = 0.f;
    #pragma unroll 8
    for (int c=0; c<64; ++c) a += pr[c]*wp[c*16];
    acc += a;
  }
  out[t] = acc;
}

// ---------------- workspace layout (bytes) ----------------
static const size_t OFF_H     = 0;           // bf16 [NN*256]; cnt_rep/fpos_rep alias here during build
static const size_t OFF_LNOUT = 25600000;    // bf16 [NN*256]
static const size_t OFF_PRE0  = 51200000;    // bf16 chunked [8][NN][32]
static const size_t OFF_PRE1  = 76800000;    // bf16 chunked [8][NN][32]
static const size_t OFF_AGG   = 102400000;   // bf16 [NN*256]
static const size_t OFF_CSR   = 128000000;   // int [800000]
static const size_t OFF_CNT   = 131200000;   // int [50000]
static const size_t OFF_OFF   = 131400064;   // int [50001]
static const size_t OFF_GOFF  = 131600128;   // int [129]
static const size_t OFF_POOL  = 131600704;   // fp32 [4][128*256]
static const size_t OFF_WT    = 132124992;   // bf16 [3][256*64]
static const size_t OFF_BSUM  = 132223296;   // int [196]
static const size_t OFF_BOFF  = 132224128;   // int [197]

extern "C" void kernel_launch(void* const* d_in, const int* in_sizes, int n_in,
                              void* d_out, int out_size, void* d_ws, size_t ws_size,
                              hipStream_t stream) {
  const float* feat = (const float*)d_in[0];
  const int*   src  = (const int*)d_in[1];
  const int*   dst  = (const int*)d_in[2];
  const int*   gid  = (const int*)d_in[3];
  const float* Wq   = (const float*)d_in[4];
  const float* Wk   = (const float*)d_in[5];
  const float* Wv   = (const float*)d_in[6];
  const float* Wo   = (const float*)d_in[7];
  const float* sg   = (const float*)d_in[8];
  const float* sb   = (const float*)d_in[9];
  const float* l1g  = (const float*)d_in[10];
  const float* l1b  = (const float*)d_in[11];
  const float* l2g  = (const float*)d_in[12];
  const float* l2b  = (const float*)d_in[13];
  const float* Wp   = (const float*)d_in[14];
  const float* bp   = (const float*)d_in[15];
  float* out = (float*)d_out;

  char* ws = (char*)d_ws;
  unsigned short* h      = (unsigned short*)(ws + OFF_H);
  unsigned short* lnout  = (unsigned short*)(ws + OFF_LNOUT);
  unsigned short* pre0   = (unsigned short*)(ws + OFF_PRE0);
  unsigned short* pre1   = (unsigned short*)(ws + OFF_PRE1);
  unsigned short* agg    = (unsigned short*)(ws + OFF_AGG);
  int*            csr    = (int*)(ws + OFF_CSR);
  int*            cnt    = (int*)(ws + OFF_CNT);
  int*            off    = (int*)(ws + OFF_OFF);
  int*            goff   = (int*)(ws + OFF_GOFF);
  float*          pooled = (float*)(ws + OFF_POOL);
  unsigned short* Wt     = (unsigned short*)(ws + OFF_WT);
  int*            bsum   = (int*)(ws + OFF_BSUM);
  int*            boff   = (int*)(ws + OFF_BOFF);
  // replicated build scratch aliases the h region (h first written by k_sab, after build)
  int*            cnt_rep  = (int*)(ws + OFF_H);
  int*            fpos_rep = (int*)(ws + OFF_H + (size_t)RREP*RSTRIDE*4);

  hipMemsetAsync(cnt_rep, 0, (size_t)RREP*RSTRIDE*4, stream);
  hipMemsetAsync(pooled, 0, 4*NG*256*sizeof(float), stream);

  // CSR for dst; graph offsets via sorted-boundary scan
  k_count_rep<<<NE/256, 256, 0, stream>>>(dst, cnt_rep, NE);
  k_goff<<<(NN+255)/256, 256, 0, stream>>>(gid, goff);
  k_reduce_rep<<<(NN+255)/256, 256, 0, stream>>>(cnt_rep, cnt);
  k_blocksum<<<196, 256, 0, stream>>>(cnt, NN, bsum);
  k_scan_small<<<1, 256, 0, stream>>>(bsum, 196, boff);
  k_scan_apply<<<196, 256, 0, stream>>>(cnt, NN, boff, off);
  k_fpos_rep<<<(NN+255)/256, 256, 0, stream>>>(cnt_rep, off, fpos_rep);
  k_fill_rep<<<NE/256, 256, 0, stream>>>(src, dst, fpos_rep, csr, NE);

  // weights transpose + feat->bf16 (chunked) + hidden_rep[0] pooling
  k_wt<<<192, 256, 0, stream>>>(Wq, Wk, Wv, Wo, Wt);
  k_f2bf_c<<<12500, 256, 0, stream>>>(feat, pre0);
  k_pool8<<<NG*8, 256, 0, stream>>>(feat, goff, pooled + 0*32768);

  int aggBlocks = 1563*8;   // 1D: chunk = blockIdx & 7 (XCD-pinned), seg = blockIdx >> 3

  // layer 0
  k_agg_x<<<aggBlocks, 256, 0, stream>>>(pre0, off, csr, agg);
  k_sab<<<3125, 256, 0, stream>>>(agg, h, lnout, pre1, Wt + 0*16384,
                                  sg + 0, sb + 0, l2g + 0, l2b + 0,
                                  l1g + 1*64, l1b + 1*64, 0, 1, 1);
  k_pool8b<<<NG*8, 256, 0, stream>>>(lnout, goff, pooled + 1*32768);

  // layer 1
  k_agg_x<<<aggBlocks, 256, 0, stream>>>(pre1, off, csr, agg);
  k_sab<<<3125, 256, 0, stream>>>(agg, h, lnout, pre0, Wt + 1*16384,
                                  sg + 1*64, sb + 1*64, l2g + 1*64, l2b + 1*64,
                                  l1g + 2*64, l1b + 2*64, 1, 1, 1);
  k_pool8b<<<NG*8, 256, 0, stream>>>(lnout, goff, pooled + 2*32768);

  // layer 2 (h/pre dead afterwards)
  k_agg_x<<<aggBlocks, 256, 0, stream>>>(pre0, off, csr, agg);
  k_sab<<<3125, 256, 0, stream>>>(agg, h, lnout, pre1, Wt + 2*16384,
                                  sg + 2*64, sb + 2*64, l2g + 2*64, l2b + 2*64,
                                  l1g + 2*64, l1b + 2*64, 1, 0, 0);
  k_pool8b<<<NG*8, 256, 0, stream>>>(lnout, goff, pooled + 3*32768);

  k_final<<<32, 256, 0, stream>>>(pooled, Wp, bp, out);
}

// Round 12
// 661.463 us; speedup vs baseline: 1.2106x; 1.2106x over previous
//
#include <hip/hip_runtime.h>

#define NN 50000
#define NE 800000
#define NG 128
#define RREP 16
#define RSTRIDE 50048

typedef __attribute__((ext_vector_type(8))) short short8;
typedef __attribute__((ext_vector_type(4))) float f32x4;

// round-half-up bf16 convert: 2 VALU ops, max err 0.5 ulp
__device__ __forceinline__ unsigned short f2bf(float f){
  union { float f; unsigned int u; } v; v.f = f;
  return (unsigned short)((v.u + 0x8000u) >> 16);
}
__device__ __forceinline__ float bf2f(unsigned short h){
  union { unsigned int u; float f; } v; v.u = ((unsigned int)h) << 16;
  return v.f;
}

// ---------------- graph offsets from SORTED graph_ids: boundary scan, zero atomics ----------------
__global__ __launch_bounds__(256) void k_goff(const int* __restrict__ gid,
                                              int* __restrict__ goff){
  int i = blockIdx.x*256 + threadIdx.x;
  if (i >= NN) return;
  int c = gid[i];
  int p = (i == 0) ? -1 : gid[i-1];
  for (int g = p+1; g <= c; ++g) goff[g] = i;
  if (i == NN-1){
    for (int g = c+1; g <= NG; ++g) goff[g] = NN;
  }
}

// ---------------- CSR build (16-way replicated histograms) ----------------
__global__ __launch_bounds__(256) void k_count_rep(const int* __restrict__ idx,
                                                   int* __restrict__ cnt_rep, int n){
  int i = blockIdx.x*256 + threadIdx.x;
  int r = blockIdx.x & (RREP-1);
  if (i < n) atomicAdd(&cnt_rep[r*RSTRIDE + idx[i]], 1);
}

__global__ __launch_bounds__(256) void k_reduce_rep(const int* __restrict__ cnt_rep,
                                                    int* __restrict__ cnt){
  int i = blockIdx.x*256 + threadIdx.x;
  if (i < NN){
    int s = 0;
    #pragma unroll
    for (int r=0; r<RREP; ++r) s += cnt_rep[r*RSTRIDE + i];
    cnt[i] = s;
  }
}

__global__ __launch_bounds__(256) void k_blocksum(const int* __restrict__ in, int n,
                                                  int* __restrict__ bsum){
  __shared__ int ws4[4];
  int i = blockIdx.x*256 + threadIdx.x;
  int v = (i < n) ? in[i] : 0;
  #pragma unroll
  for (int d=1; d<64; d<<=1) v += __shfl_xor(v, d);
  int lane = threadIdx.x & 63, w = threadIdx.x >> 6;
  if (lane == 0) ws4[w] = v;
  __syncthreads();
  if (threadIdx.x == 0) bsum[blockIdx.x] = ws4[0]+ws4[1]+ws4[2]+ws4[3];
}

// exclusive scan of n<=256 elements, single block of 256; out[n]=total
__global__ __launch_bounds__(256) void k_scan_small(const int* __restrict__ in, int n,
                                                    int* __restrict__ out){
  __shared__ int wsum[4];
  int tid = threadIdx.x, lane = tid & 63, w = tid >> 6;
  int v = (tid < n) ? in[tid] : 0;
  int x = v;
  #pragma unroll
  for (int d=1; d<64; d<<=1){ int y = __shfl_up(x, d); if (lane >= d) x += y; }
  if (lane == 63) wsum[w] = x;
  __syncthreads();
  int pre2 = 0;
  for (int j=0; j<w; ++j) pre2 += wsum[j];
  int incl = x + pre2;
  if (tid < n) out[tid] = incl - v;
  if (tid == n-1) out[n] = incl;
}

__global__ __launch_bounds__(256) void k_scan_apply(const int* __restrict__ in, int n,
                                                    const int* __restrict__ boff,
                                                    int* __restrict__ out){
  __shared__ int wsum[4];
  int tid = threadIdx.x, lane = tid & 63, w = tid >> 6;
  int i = blockIdx.x*256 + tid;
  int v = (i < n) ? in[i] : 0;
  int x = v;
  #pragma unroll
  for (int d=1; d<64; d<<=1){ int y = __shfl_up(x, d); if (lane >= d) x += y; }
  if (lane == 63) wsum[w] = x;
  __syncthreads();
  int pre2 = boff[blockIdx.x];
  for (int j=0; j<w; ++j) pre2 += wsum[j];
  int excl = x - v + pre2;
  if (i < n){
    out[i] = excl;
    if (i == n-1) out[n] = excl + v;
  }
}

// per-replica fill cursors
__global__ __launch_bounds__(256) void k_fpos_rep(const int* __restrict__ cnt_rep,
                                                  const int* __restrict__ off,
                                                  int* __restrict__ fpos_rep){
  int i = blockIdx.x*256 + threadIdx.x;
  if (i < NN){
    int p = off[i];
    #pragma unroll
    for (int r=0; r<RREP; ++r){
      fpos_rep[r*RSTRIDE + i] = p;
      p += cnt_rep[r*RSTRIDE + i];
    }
  }
}

__global__ __launch_bounds__(256) void k_fill_rep(const int* __restrict__ src,
                                                  const int* __restrict__ dst,
                                                  int* __restrict__ fpos_rep,
                                                  int* __restrict__ csr, int n){
  int i = blockIdx.x*256 + threadIdx.x;
  int r = blockIdx.x & (RREP-1);
  if (i < n){
    int p = atomicAdd(&fpos_rep[r*RSTRIDE + dst[i]], 1);
    csr[p] = src[i];
  }
}

// ---------------- weight pre-transpose to bf16 ----------------
__global__ __launch_bounds__(256) void k_wt(const float* __restrict__ Wq,
                                            const float* __restrict__ Wk,
                                            const float* __restrict__ Wv,
                                            const float* __restrict__ Wo,
                                            unsigned short* __restrict__ Wt){
  int gid = blockIdx.x*256 + threadIdx.x;   // 49152 total
  int l   = gid >> 14;
  int rem = gid & 16383;
  int mat = rem >> 12;
  int idx = rem & 4095;
  int c = idx >> 6, n = idx & 63;
  const float* srcp = (mat==0)?Wq:(mat==1)?Wk:(mat==2)?Wv:Wo;
  float v = srcp[l*4096 + idx];
  Wt[l*16384 + (mat*64 + n)*64 + c] = f2bf(v);
}

// ---------------- fp32 -> bf16, CHUNKED pre layout: [8 chunks][NN nodes][32 feats] ----------------
__global__ __launch_bounds__(256) void k_f2bf_c(const float* __restrict__ in,
                                                unsigned short* __restrict__ out){
  int i = blockIdx.x*256 + threadIdx.x;   // ushort4 id, 3,200,000 total
  float4 v = ((const float4*)in)[i];
  ushort4 o; o.x=f2bf(v.x); o.y=f2bf(v.y); o.z=f2bf(v.z); o.w=f2bf(v.w);
  int flat = i << 2;
  int node = flat >> 8, f = flat & 255;
  int chunk = f >> 5;
  ((ushort4*)out)[(size_t)chunk*NN*8 + node*8 + ((f & 31) >> 2)] = o;
}

// ---------------- XCD-pinned chunked CSR gather ----------------
// csr: NORMAL loads (address-critical path; must stay L2-resident across the 8 chunk replays).
// agg store: NON-TEMPORAL (off critical path; keeps L2 clean for table -> FETCH 188->50MB, r11).
__global__ __launch_bounds__(256) void k_agg_x(const unsigned short* __restrict__ pre_c,
                                               const int* __restrict__ off,
                                               const int* __restrict__ csr,
                                               unsigned short* __restrict__ agg){
  int chunk = blockIdx.x & 7;
  int seg   = blockIdx.x >> 3;
  int w = threadIdx.x >> 6, lane = threadIdx.x & 63;
  int lg = lane >> 3, li = lane & 7;
  int node = seg*32 + w*8 + lg;
  if (node >= NN) return;
  const ushort4* slice = (const ushort4*)pre_c + (size_t)chunk*NN*8;
  int s = off[node], e = off[node+1];
  ushort4 u = slice[node*8 + li];
  float a0 = bf2f(u.x), a1 = bf2f(u.y), a2 = bf2f(u.z), a3 = bf2f(u.w);
  int i = s;
  for (; i + 2 <= e; i += 2){
    int n0 = csr[i], n1 = csr[i+1];
    ushort4 u0 = slice[n0*8 + li], u1 = slice[n1*8 + li];
    a0 += bf2f(u0.x)+bf2f(u1.x);
    a1 += bf2f(u0.y)+bf2f(u1.y);
    a2 += bf2f(u0.z)+bf2f(u1.z);
    a3 += bf2f(u0.w)+bf2f(u1.w);
  }
  if (i < e){
    int n0 = csr[i];
    ushort4 u0 = slice[n0*8 + li];
    a0 += bf2f(u0.x); a1 += bf2f(u0.y); a2 += bf2f(u0.z); a3 += bf2f(u0.w);
  }
  ushort4 o; o.x=f2bf(a0); o.y=f2bf(a1); o.z=f2bf(a2); o.w=f2bf(a3);
  union { ushort4 v; unsigned long long u; } cvt; cvt.v = o;
  __builtin_nontemporal_store(cvt.u,
      (unsigned long long*)&((ushort4*)agg)[node*64 + chunk*8 + li]);
}

// ---------------- SAB (r7 proven structure + register agg residual):
// LN -> QKV MFMA -> distributed LDS attention -> O-proj MFMA -> residual -> epilogue
__global__ __launch_bounds__(256) void k_sab(const unsigned short* __restrict__ agg,
                                             unsigned short* __restrict__ h,
                                             unsigned short* __restrict__ lnout,
                                             unsigned short* __restrict__ pre_next,
                                             const unsigned short* __restrict__ Wt,
                                             const float* __restrict__ lng,
                                             const float* __restrict__ lnb,
                                             const float* __restrict__ g2,
                                             const float* __restrict__ b2,
                                             const float* __restrict__ g1,
                                             const float* __restrict__ b1,
                                             int residual, int write_pre, int write_h){
  __shared__ unsigned short xo_s[4][16][72];    // xin -> o -> val (aliased through phases)
  __shared__ unsigned short qkv_s[4][16][200];  // cols 0..63 q, 64..127 k, 128..191 v

  int tid = threadIdx.x;
  int w = tid >> 6, lane = tid & 63;
  int c16 = lane & 15, kb = lane >> 4;
  int R0 = blockIdx.x*64 + w*16;   // 16 contiguous global rows (4 nodes)

  // phase 1: read agg (bf16), keep raw in regs for residual, LN -> bf16 A-staging
  ushort4 av[4];
  {
    float4 gv = ((const float4*)lng)[c16];
    float4 bv = ((const float4*)lnb)[c16];
    #pragma unroll
    for (int rr=0; rr<4; ++rr){
      int m = rr*4 + kb;
      ushort4 uv = ((const ushort4*)agg)[(R0+m)*16 + c16];
      av[rr] = uv;
      float vx = bf2f(uv.x), vy = bf2f(uv.y), vz = bf2f(uv.z), vw = bf2f(uv.w);
      float s = vx+vy+vz+vw;
      float q = vx*vx+vy*vy+vz*vz+vw*vw;
      #pragma unroll
      for (int d=1; d<16; d<<=1){ s += __shfl_xor(s, d); q += __shfl_xor(q, d); }
      float mu = s*(1.f/64.f);
      float rs = rsqrtf(q*(1.f/64.f) - mu*mu + 1e-5f);
      ushort4 o;
      o.x=f2bf((vx-mu)*rs*gv.x+bv.x); o.y=f2bf((vy-mu)*rs*gv.y+bv.y);
      o.z=f2bf((vz-mu)*rs*gv.z+bv.z); o.w=f2bf((vw-mu)*rs*gv.w+bv.w);
      *(ushort4*)&xo_s[w][m][c16*4] = o;
    }
  }

  // phase 2: QKV = xin @ Wqkv  (A-frag: row=c16, k=kb*8+j)
  short8 a0v = *(const short8*)&xo_s[w][c16][kb*8];
  short8 a1v = *(const short8*)&xo_s[w][c16][32 + kb*8];
  f32x4 acc[12];
  #pragma unroll
  for (int t=0; t<12; ++t){
    short8 b0 = *(const short8*)&Wt[(t*16 + c16)*64 + kb*8];
    short8 b1 = *(const short8*)&Wt[(t*16 + c16)*64 + 32 + kb*8];
    f32x4 z = {0.f, 0.f, 0.f, 0.f};
    z = __builtin_amdgcn_mfma_f32_16x16x32_bf16(a0v, b0, z, 0, 0, 0);
    z = __builtin_amdgcn_mfma_f32_16x16x32_bf16(a1v, b1, z, 0, 0, 0);
    acc[t] = z;
  }
  // C/D layout: col=lane&15, row=(lane>>4)*4+reg
  #pragma unroll
  for (int t=0; t<12; ++t){
    #pragma unroll
    for (int r=0; r<4; ++r)
      qkv_s[w][kb*4 + r][t*16 + c16] = f2bf(acc[t][r]);
  }

  // phase 3: distributed attention, per (node, head, q-row) lane (r7, proven)
  {
    int p = lane >> 2, qr = lane & 3;
    int ns = p >> 2, hd = p & 3;
    int mrow = ns*4 + qr;
    int qc = hd*16, kc = 64 + hd*16, vc = 128 + hd*16;
    float qv[16];
    short8 u0 = *(const short8*)&qkv_s[w][mrow][qc];
    short8 u1 = *(const short8*)&qkv_s[w][mrow][qc+8];
    #pragma unroll
    for (int j=0; j<8; ++j){
      qv[j]   = bf2f((unsigned short)u0[j]);
      qv[8+j] = bf2f((unsigned short)u1[j]);
    }
    float sc[4];
    #pragma unroll
    for (int kr=0; kr<4; ++kr){
      short8 k0 = *(const short8*)&qkv_s[w][ns*4+kr][kc];
      short8 k1 = *(const short8*)&qkv_s[w][ns*4+kr][kc+8];
      float d2 = 0.f;
      #pragma unroll
      for (int j=0; j<8; ++j){
        d2 += qv[j]  *bf2f((unsigned short)k0[j]);
        d2 += qv[8+j]*bf2f((unsigned short)k1[j]);
      }
      sc[kr] = d2 * 0.25f;   // 1/sqrt(16)
    }
    float mx = fmaxf(fmaxf(sc[0],sc[1]), fmaxf(sc[2],sc[3]));
    float e0=__expf(sc[0]-mx), e1=__expf(sc[1]-mx), e2=__expf(sc[2]-mx), e3=__expf(sc[3]-mx);
    float inv = 1.f/(e0+e1+e2+e3);
    float at[4] = {e0*inv, e1*inv, e2*inv, e3*inv};
    float ov[16];
    #pragma unroll
    for (int j=0; j<16; ++j) ov[j] = 0.f;
    #pragma unroll
    for (int kr=0; kr<4; ++kr){
      short8 v0 = *(const short8*)&qkv_s[w][ns*4+kr][vc];
      short8 v1 = *(const short8*)&qkv_s[w][ns*4+kr][vc+8];
      #pragma unroll
      for (int j=0; j<8; ++j){
        ov[j]   += at[kr]*bf2f((unsigned short)v0[j]);
        ov[8+j] += at[kr]*bf2f((unsigned short)v1[j]);
      }
    }
    short8 s0v, s1v;
    #pragma unroll
    for (int j=0; j<8; ++j){
      s0v[j] = (short)f2bf(ov[j]);
      s1v[j] = (short)f2bf(ov[8+j]);
    }
    *(short8*)&xo_s[w][mrow][qc]   = s0v;
    *(short8*)&xo_s[w][mrow][qc+8] = s1v;
  }

  // phase 4: val = o @ Wo, C-layout -> LDS (back to row-major view)
  {
    short8 oa0 = *(const short8*)&xo_s[w][c16][kb*8];
    short8 oa1 = *(const short8*)&xo_s[w][c16][32 + kb*8];
    #pragma unroll
    for (int t=0; t<4; ++t){
      short8 b0 = *(const short8*)&Wt[(192 + t*16 + c16)*64 + kb*8];
      short8 b1 = *(const short8*)&Wt[(192 + t*16 + c16)*64 + 32 + kb*8];
      f32x4 z = {0.f, 0.f, 0.f, 0.f};
      z = __builtin_amdgcn_mfma_f32_16x16x32_bf16(oa0, b0, z, 0, 0, 0);
      z = __builtin_amdgcn_mfma_f32_16x16x32_bf16(oa1, b1, z, 0, 0, 0);
      #pragma unroll
      for (int r=0; r<4; ++r)
        xo_s[w][kb*4 + r][t*16 + c16] = f2bf(z[r]);
    }
  }

  // epilogue: coalesced ushort4 streams; iter rr handles row m=rr*4+kb (matches av[rr])
  float4 g2v = ((const float4*)g2)[c16];
  float4 b2v = ((const float4*)b2)[c16];
  float4 g1v, b1v;
  if (write_pre){ g1v = ((const float4*)g1)[c16]; b1v = ((const float4*)b1)[c16]; }
  #pragma unroll
  for (int rr=0; rr<4; ++rr){
    int m = rr*4 + kb;
    int row = R0 + m;
    ushort4 uv = *(const ushort4*)&xo_s[w][m][c16*4];
    float v0 = bf2f(uv.x), v1 = bf2f(uv.y), v2 = bf2f(uv.z), v3 = bf2f(uv.w);
    if (residual){
      ushort4 hh = ((const ushort4*)h)[row*16 + c16];
      v0 += bf2f(hh.x) + bf2f(av[rr].x);
      v1 += bf2f(hh.y) + bf2f(av[rr].y);
      v2 += bf2f(hh.z) + bf2f(av[rr].z);
      v3 += bf2f(hh.w) + bf2f(av[rr].w);
    }
    float r0 = fmaxf(v0,0.f), r1 = fmaxf(v1,0.f), r2 = fmaxf(v2,0.f), r3 = fmaxf(v3,0.f);
    float s1 = v0+v1+v2+v3, q1 = v0*v0+v1*v1+v2*v2+v3*v3;
    float s2 = r0+r1+r2+r3, q2 = r0*r0+r1*r1+r2*r2+r3*r3;
    #pragma unroll
    for (int d=1; d<16; d<<=1){
      s1 += __shfl_xor(s1, d); q1 += __shfl_xor(q1, d);
      s2 += __shfl_xor(s2, d); q2 += __shfl_xor(q2, d);
    }
    float mu1 = s1*(1.f/64.f), rs1 = rsqrtf(q1*(1.f/64.f) - mu1*mu1 + 1e-5f);
    float mu2 = s2*(1.f/64.f), rs2 = rsqrtf(q2*(1.f/64.f) - mu2*mu2 + 1e-5f);
    if (write_h){
      ushort4 o; o.x=f2bf(v0); o.y=f2bf(v1); o.z=f2bf(v2); o.w=f2bf(v3);
      ((ushort4*)h)[row*16 + c16] = o;
    }
    {
      ushort4 o;
      o.x=f2bf((r0-mu2)*rs2*g2v.x+b2v.x); o.y=f2bf((r1-mu2)*rs2*g2v.y+b2v.y);
      o.z=f2bf((r2-mu2)*rs2*g2v.z+b2v.z); o.w=f2bf((r3-mu2)*rs2*g2v.w+b2v.w);
      ((ushort4*)lnout)[row*16 + c16] = o;
    }
    if (write_pre){
      int nd = row >> 2;
      int f = (row & 3)*64 + 4*c16;
      int chunk = f >> 5;
      ushort4 o;
      o.x=f2bf((v0-mu1)*rs1*g1v.x+b1v.x); o.y=f2bf((v1-mu1)*rs1*g1v.y+b1v.y);
      o.z=f2bf((v2-mu1)*rs1*g1v.z+b1v.z); o.w=f2bf((v3-mu1)*rs1*g1v.w+b1v.w);
      ((ushort4*)pre_next)[(size_t)chunk*NN*8 + nd*8 + ((f & 31) >> 2)] = o;
    }
  }
}

// ---------------- per-graph pooling: 8 sub-blocks per graph, atomic merge ----------------
__global__ __launch_bounds__(256) void k_pool8(const float* __restrict__ src,
                                               const int* __restrict__ goff,
                                               float* __restrict__ out){
  int g = blockIdx.x >> 3, sub = blockIdx.x & 7, t = threadIdx.x;
  int s = goff[g], e = goff[g+1], len = e - s;
  int s0 = s + ((len*sub) >> 3), e0 = s + ((len*(sub+1)) >> 3);
  float a0=0.f, a1=0.f;
  int n = s0;
  for (; n + 2 <= e0; n += 2){ a0 += src[n*256 + t]; a1 += src[(n+1)*256 + t]; }
  if (n < e0) a0 += src[n*256 + t];
  atomicAdd(&out[g*256 + t], a0 + a1);
}

__global__ __launch_bounds__(256) void k_pool8b(const unsigned short* __restrict__ src,
                                                const int* __restrict__ goff,
                                                float* __restrict__ out){
  int g = blockIdx.x >> 3, sub = blockIdx.x & 7, t = threadIdx.x;
  int s = goff[g], e = goff[g+1], len = e - s;
  int s0 = s + ((len*sub) >> 3), e0 = s + ((len*(sub+1)) >> 3);
  float a0=0.f, a1=0.f;
  int n = s0;
  for (; n + 2 <= e0; n += 2){ a0 += bf2f(src[n*256 + t]); a1 += bf2f(src[(n+1)*256 + t]); }
  if (n < e0) a0 += bf2f(src[n*256 + t]);
  atomicAdd(&out[g*256 + t], a0 + a1);
}

// ---------------- final: score = sum_i pooled_i @ W_pred[i] + b_pred[i] ----------------
__global__ __launch_bounds__(256) void k_final(const float* __restrict__ pooled,
                                               const float* __restrict__ Wp,
                                               const float* __restrict__ bp,
                                               float* __restrict__ out){
  int t = blockIdx.x*256 + threadIdx.x;  // 8192 = 128*4*16
  int b = t >> 6, s = (t >> 4) & 3, o = t & 15;
  float acc = 0.f;
  for (int i=0; i<4; ++i){
    acc += bp[i*16 + o];
    const float* pr = pooled + i*32768 + b*256 + s*64;
    const float* wp = Wp + i*1024 + o;
    float a = 0.f;
    #pragma unroll 8
    for (int c=0; c<64; ++c) a += pr[c]*wp[c*16];
    acc += a;
  }
  out[t] = acc;
}

// ---------------- workspace layout (bytes) ----------------
static const size_t OFF_H     = 0;           // bf16 [NN*256]; cnt_rep/fpos_rep alias here during build
static const size_t OFF_LNOUT = 25600000;    // bf16 [NN*256]
static const size_t OFF_PRE0  = 51200000;    // bf16 chunked [8][NN][32]
static const size_t OFF_PRE1  = 76800000;    // bf16 chunked [8][NN][32]
static const size_t OFF_AGG   = 102400000;   // bf16 [NN*256]
static const size_t OFF_CSR   = 128000000;   // int [800000]
static const size_t OFF_CNT   = 131200000;   // int [50000]
static const size_t OFF_OFF   = 131400064;   // int [50001]
static const size_t OFF_GOFF  = 131600128;   // int [129]
static const size_t OFF_POOL  = 131600704;   // fp32 [4][128*256]
static const size_t OFF_WT    = 132124992;   // bf16 [3][256*64]
static const size_t OFF_BSUM  = 132223296;   // int [196]
static const size_t OFF_BOFF  = 132224128;   // int [197]

extern "C" void kernel_launch(void* const* d_in, const int* in_sizes, int n_in,
                              void* d_out, int out_size, void* d_ws, size_t ws_size,
                              hipStream_t stream) {
  const float* feat = (const float*)d_in[0];
  const int*   src  = (const int*)d_in[1];
  const int*   dst  = (const int*)d_in[2];
  const int*   gid  = (const int*)d_in[3];
  const float* Wq   = (const float*)d_in[4];
  const float* Wk   = (const float*)d_in[5];
  const float* Wv   = (const float*)d_in[6];
  const float* Wo   = (const float*)d_in[7];
  const float* sg   = (const float*)d_in[8];
  const float* sb   = (const float*)d_in[9];
  const float* l1g  = (const float*)d_in[10];
  const float* l1b  = (const float*)d_in[11];
  const float* l2g  = (const float*)d_in[12];
  const float* l2b  = (const float*)d_in[13];
  const float* Wp   = (const float*)d_in[14];
  const float* bp   = (const float*)d_in[15];
  float* out = (float*)d_out;

  char* ws = (char*)d_ws;
  unsigned short* h      = (unsigned short*)(ws + OFF_H);
  unsigned short* lnout  = (unsigned short*)(ws + OFF_LNOUT);
  unsigned short* pre0   = (unsigned short*)(ws + OFF_PRE0);
  unsigned short* pre1   = (unsigned short*)(ws + OFF_PRE1);
  unsigned short* agg    = (unsigned short*)(ws + OFF_AGG);
  int*            csr    = (int*)(ws + OFF_CSR);
  int*            cnt    = (int*)(ws + OFF_CNT);
  int*            off    = (int*)(ws + OFF_OFF);
  int*            goff   = (int*)(ws + OFF_GOFF);
  float*          pooled = (float*)(ws + OFF_POOL);
  unsigned short* Wt     = (unsigned short*)(ws + OFF_WT);
  int*            bsum   = (int*)(ws + OFF_BSUM);
  int*            boff   = (int*)(ws + OFF_BOFF);
  // replicated build scratch aliases the h region (h first written by k_sab, after build)
  int*            cnt_rep  = (int*)(ws + OFF_H);
  int*            fpos_rep = (int*)(ws + OFF_H + (size_t)RREP*RSTRIDE*4);

  hipMemsetAsync(cnt_rep, 0, (size_t)RREP*RSTRIDE*4, stream);
  hipMemsetAsync(pooled, 0, 4*NG*256*sizeof(float), stream);

  // CSR for dst; graph offsets via sorted-boundary scan
  k_count_rep<<<NE/256, 256, 0, stream>>>(dst, cnt_rep, NE);
  k_goff<<<(NN+255)/256, 256, 0, stream>>>(gid, goff);
  k_reduce_rep<<<(NN+255)/256, 256, 0, stream>>>(cnt_rep, cnt);
  k_blocksum<<<196, 256, 0, stream>>>(cnt, NN, bsum);
  k_scan_small<<<1, 256, 0, stream>>>(bsum, 196, boff);
  k_scan_apply<<<196, 256, 0, stream>>>(cnt, NN, boff, off);
  k_fpos_rep<<<(NN+255)/256, 256, 0, stream>>>(cnt_rep, off, fpos_rep);
  k_fill_rep<<<NE/256, 256, 0, stream>>>(src, dst, fpos_rep, csr, NE);

  // weights transpose + feat->bf16 (chunked) + hidden_rep[0] pooling
  k_wt<<<192, 256, 0, stream>>>(Wq, Wk, Wv, Wo, Wt);
  k_f2bf_c<<<12500, 256, 0, stream>>>(feat, pre0);
  k_pool8<<<NG*8, 256, 0, stream>>>(feat, goff, pooled + 0*32768);

  int aggBlocks = 1563*8;   // 1D: chunk = blockIdx & 7 (XCD-pinned), seg = blockIdx >> 3

  // layer 0
  k_agg_x<<<aggBlocks, 256, 0, stream>>>(pre0, off, csr, agg);
  k_sab<<<3125, 256, 0, stream>>>(agg, h, lnout, pre1, Wt + 0*16384,
                                  sg + 0, sb + 0, l2g + 0, l2b + 0,
                                  l1g + 1*64, l1b + 1*64, 0, 1, 1);
  k_pool8b<<<NG*8, 256, 0, stream>>>(lnout, goff, pooled + 1*32768);

  // layer 1
  k_agg_x<<<aggBlocks, 256, 0, stream>>>(pre1, off, csr, agg);
  k_sab<<<3125, 256, 0, stream>>>(agg, h, lnout, pre0, Wt + 1*16384,
                                  sg + 1*64, sb + 1*64, l2g + 1*64, l2b + 1*64,
                                  l1g + 2*64, l1b + 2*64, 1, 1, 1);
  k_pool8b<<<NG*8, 256, 0, stream>>>(lnout, goff, pooled + 2*32768);

  // layer 2 (h/pre dead afterwards)
  k_agg_x<<<aggBlocks, 256, 0, stream>>>(pre0, off, csr, agg);
  k_sab<<<3125, 256, 0, stream>>>(agg, h, lnout, pre1, Wt + 2*16384,
                                  sg + 2*64, sb + 2*64, l2g + 2*64, l2b + 2*64,
                                  l1g + 2*64, l1b + 2*64, 1, 0, 0);
  k_pool8b<<<NG*8, 256, 0, stream>>>(lnout, goff, pooled + 3*32768);

  k_final<<<32, 256, 0, stream>>>(pooled, Wp, bp, out);
}